// Round 6
// baseline (6256.717 us; speedup 1.0000x reference)
//
#include <hip/hip_runtime.h>

// Problem constants
#define Bn 4
#define Nn 8192
#define Dn 64
#define Sn 2048
#define Kn 32
#define R2c 0.04f          // f32(0.2*0.2)
#define OUT_XYZ (Bn*Sn*3)  // 24576 floats of new_xyz, then feats

// Workspace layout (units = 4-byte elements)
#define WS_P4  0            // [B*N] float4 {x,y,z,0}
#define WS_WB1 131072       // bf16 W1' [64][96]  (feat-first permute, zero pad)
#define WS_WB2 134144       // bf16 W2  [128][64]
#define WS_WB3 138240       // bf16 W3  [256][128]
#define WS_GRP 154624       // int grp_idx [B*S][K]

#define HSTR 136            // bf16 LDS row stride (128 max C + 8 pad)

typedef __attribute__((ext_vector_type(8))) short short8;
typedef __attribute__((ext_vector_type(4))) float floatx4;
typedef __attribute__((ext_vector_type(2))) float float2v;
typedef unsigned long long ull;

// float -> bf16 (RNE) without relying on header APIs
__device__ __forceinline__ unsigned short f2bf(float f) {
    unsigned u = __float_as_uint(f);
    return (unsigned short)((u + 0x7FFFu + ((u >> 16) & 1u)) >> 16);
}

// ---------------------------------------------------------------------------
// Prep: xyz -> float4 array; weights -> bf16 [O][Cp] row-major.
// ---------------------------------------------------------------------------
__global__ __launch_bounds__(256) void prep_kernel(const float* __restrict__ xyz,
                                                   const float* __restrict__ W1,
                                                   const float* __restrict__ W2,
                                                   const float* __restrict__ W3,
                                                   float* __restrict__ ws) {
    int id = blockIdx.x * 256 + threadIdx.x;
    if (id < Bn * Nn) {
        float4* p4 = (float4*)(ws + WS_P4);
        p4[id] = make_float4(xyz[id * 3 + 0], xyz[id * 3 + 1], xyz[id * 3 + 2], 0.f);
    }
    int i1 = id - Bn * Nn;
    if (i1 >= 0 && i1 < 64 * 96) {
        int o = i1 / 96, c = i1 % 96;
        float v = (c < 64) ? W1[o * 67 + 3 + c] : (c < 67 ? W1[o * 67 + (c - 64)] : 0.f);
        ((unsigned short*)(ws + WS_WB1))[i1] = f2bf(v);
    }
    int i2 = i1 - 64 * 96;
    if (i2 >= 0 && i2 < 128 * 64)
        ((unsigned short*)(ws + WS_WB2))[i2] = f2bf(W2[i2]);
    int i3 = i2 - 128 * 64;
    if (i3 >= 0 && i3 < 256 * 128)
        ((unsigned short*)(ws + WS_WB3))[i3] = f2bf(W3[i3]);
}

// Fused wave-64 lexicographic max of 64-bit keys (hi=dist bits, lo=payload).
// One DPP ladder; 0-injection from bound_ctrl can never win. Result
// broadcast via 2 readlanes from lane 63 (SGPR-uniform).
__device__ __forceinline__ ull wave_kmax_dpp(ull k) {
    unsigned lo = (unsigned)k, hi = (unsigned)(k >> 32);
#define KRUNG(ctl)                                                                          \
    {                                                                                       \
        unsigned tlo = (unsigned)__builtin_amdgcn_update_dpp(0, (int)lo, ctl, 0xf, 0xf, true); \
        unsigned thi = (unsigned)__builtin_amdgcn_update_dpp(0, (int)hi, ctl, 0xf, 0xf, true); \
        ull t = ((ull)thi << 32) | tlo;                                                     \
        ull c = ((ull)hi << 32) | lo;                                                       \
        if (t > c) { hi = thi; lo = tlo; }                                                  \
    }
    KRUNG(0x111) KRUNG(0x112) KRUNG(0x114) KRUNG(0x118) KRUNG(0x142) KRUNG(0x143)
#undef KRUNG
    hi = (unsigned)__builtin_amdgcn_readlane((int)hi, 63);
    lo = (unsigned)__builtin_amdgcn_readlane((int)lo, 63);
    return ((ull)hi << 32) | lo;
}

// One slab's conditional distance update + key reduce (wave 0 only).
// Q = slab id (points at LDS slots [Q*1024, Q*1024+1024)).
// dq = this slab's dist state in registers (8 float2v = 8 pt-pairs/lane,
// pair u = slots Q*1024+u*128+lane and +64). Skipped (cached kq/wq stay
// valid) iff the slab's z-bbox is provably farther than wq: dists only
// decrease, so min(dist,d)=dist for every slab point -> bit-exact.
template<int Q>
__device__ __forceinline__ void slab_step(const float4* __restrict__ sP4,
                                          float2 bbq, float cz,
                                          float2v nX, float2v nY, float2v nZ,
                                          float2v (&dq)[8], ull& kq, float& wq,
                                          int lane) {
    float dzb = fmaxf(fmaxf(bbq.x - cz, cz - bbq.y), 0.0f);
    if (!(dzb * dzb * 0.999999f < wq)) return;   // wave-uniform skip

    float lv = -1.0f;
    unsigned lo_[16];
    #pragma unroll
    for (int u = 0; u < 8; u++) {
        int saA = Q * 1024 + u * 128 + lane;     // canonical 16B/lane reads
        int saB = saA + 64;
        float4 va = sP4[saA];
        float4 vb = sP4[saB];
        unsigned ogA = (unsigned)__float_as_int(va.w);
        unsigned ogB = (unsigned)__float_as_int(vb.w);
        lo_[2 * u]     = ((8191u - ogA) << 13) | (unsigned)saA;
        lo_[2 * u + 1] = ((8191u - ogB) << 13) | (unsigned)saB;
        float2v px, py, pz;
        px.x = va.x; px.y = vb.x;
        py.x = va.y; py.y = vb.y;
        pz.x = va.z; pz.y = vb.z;
        float2v dx, dy, dz_, xx, yy, zz, s1, d2;
        asm("v_pk_add_f32 %0, %1, %2" : "=v"(dx) : "v"(px), "v"(nX));
        asm("v_pk_add_f32 %0, %1, %2" : "=v"(dy) : "v"(py), "v"(nY));
        asm("v_pk_add_f32 %0, %1, %2" : "=v"(dz_) : "v"(pz), "v"(nZ));
        asm("v_pk_mul_f32 %0, %1, %1" : "=v"(xx) : "v"(dx));
        asm("v_pk_mul_f32 %0, %1, %1" : "=v"(yy) : "v"(dy));
        asm("v_pk_mul_f32 %0, %1, %1" : "=v"(zz) : "v"(dz_));
        asm("v_pk_add_f32 %0, %1, %2" : "=v"(s1) : "v"(xx), "v"(yy));
        asm("v_pk_add_f32 %0, %1, %2" : "=v"(d2) : "v"(s1), "v"(zz));
        float mx = fminf(dq[u].x, d2.x);
        float my = fminf(dq[u].y, d2.y);
        dq[u].x = mx; dq[u].y = my;
        lv = fmaxf(fmaxf(lv, mx), my);           // v_max3_f32
    }

    // lane-tie recovery: max lo among THIS lane's points at lv
    unsigned c_[16];
    #pragma unroll
    for (int u = 0; u < 8; u++) {
        c_[2 * u]     = (dq[u].x == lv) ? lo_[2 * u]     : 0u;
        c_[2 * u + 1] = (dq[u].y == lv) ? lo_[2 * u + 1] : 0u;
    }
    #pragma unroll
    for (int st = 1; st < 16; st <<= 1)
        #pragma unroll
        for (int i = 0; i < 16; i += 2 * st)
            c_[i] = (c_[i + st] > c_[i]) ? c_[i + st] : c_[i];

    ull kk = ((ull)__float_as_uint(lv) << 32) | (ull)c_[0];
    kq = wave_kmax_dpp(kk);
    wq = __uint_as_float((unsigned)(kq >> 32));
}

// ---------------------------------------------------------------------------
// Farthest point sampling — SINGLE-WAVE version (no per-step barrier).
//
// Prologue (all 8 waves): z-sort 8192 points (256-bin counting sort) into a
// 128KB LDS table sP4 (x,y,z,origIdx), per-slab exact z-bboxes -> LDS.
// Waves 1-7 then EXIT. Wave 0 holds dist[] for all 8 slabs in 128 VGPRs
// (8 static arrays, template-indexed -> no dynamic reg indexing) and runs
// the whole FPS loop alone: 8 uniform bbox skip-tests, distance update only
// for active slabs (LDS reads, canonical 16B/lane pattern), fused u64 DPP
// ladder per active slab, 7-compare register key tree, broadcast LDS winner
// fetch. Deletes per step: s_barrier, LDS key exchange, 7x redundant skip
// checks/trees, all cross-wave coordination.
//
// Exactness: identical per-point FP ops and key tie-break as R4/R5 (passed);
// per-slab cached keys valid under the conservative skip (dists only
// decrease); global winner = max over per-slab keys. Sort is a permutation;
// payload carries original index.
// ---------------------------------------------------------------------------
__global__ __launch_bounds__(512, 2) void fps_kernel(const float* __restrict__ ws,
                                                     float* __restrict__ out_xyz) {
    #pragma clang fp contract(off)
    const int b = blockIdx.x;
    const int tid = threadIdx.x;
    const int lane = tid & 63;
    const int wv = tid >> 6;
    const float4* p4 = (const float4*)(ws + WS_P4) + b * Nn;

    __shared__ __align__(16) float4 sP4[Nn];   // 128 KB sorted point table
    __shared__ float2 sBB[8];                  // per-slab z-bbox
    __shared__ int sH[256];                    // histogram
    __shared__ int sC[256];                    // cursors (exclusive starts)

    // ---- load original points (coalesced) ----
    float4 t4[16];
    #pragma unroll
    for (int j = 0; j < 16; j++) t4[j] = p4[j * 512 + tid];

    // ---- histogram over 256 z-bins ----
    for (int i = tid; i < 256; i += 512) sH[i] = 0;
    __syncthreads();
    int slt[16];
    #pragma unroll
    for (int j = 0; j < 16; j++) {
        int bin = (int)(t4[j].z * 256.0f);
        bin = bin < 0 ? 0 : (bin > 255 ? 255 : bin);
        slt[j] = bin;
        atomicAdd(&sH[bin], 1);
    }
    __syncthreads();

    // ---- exclusive scan of 256 bins (wave 0, 4 bins/lane) ----
    if (tid < 64) {
        int b4 = tid * 4;
        int h0 = sH[b4], h1 = sH[b4 + 1], h2 = sH[b4 + 2], h3 = sH[b4 + 3];
        int sum = h0 + h1 + h2 + h3;
        int inc = sum;
        #pragma unroll
        for (int off = 1; off < 64; off <<= 1) {
            int o = __shfl_up(inc, off);
            if (tid >= off) inc += o;
        }
        int exc = inc - sum;
        sC[b4]     = exc;
        sC[b4 + 1] = exc + h0;
        sC[b4 + 2] = exc + h0 + h1;
        sC[b4 + 3] = exc + h0 + h1 + h2;
    }
    __syncthreads();

    // ---- claim unique sorted slots, scatter into the table ----
    #pragma unroll
    for (int j = 0; j < 16; j++)
        slt[j] = atomicAdd(&sC[slt[j]], 1);
    #pragma unroll
    for (int j = 0; j < 16; j++)
        sP4[slt[j]] = make_float4(t4[j].x, t4[j].y, t4[j].z,
                                  __int_as_float(j * 512 + tid));
    __syncthreads();

    // ---- per-wave slab z-bbox (exact butterfly), one time ----
    {
        float zl = 1e30f, zh = -1e30f;
        #pragma unroll
        for (int u = 0; u < 16; u++) {
            float z = sP4[wv * 1024 + u * 64 + lane].z;
            zl = fminf(zl, z);
            zh = fmaxf(zh, z);
        }
        #pragma unroll
        for (int off = 1; off < 64; off <<= 1) {
            zl = fminf(zl, __shfl_xor(zl, off));
            zh = fmaxf(zh, __shfl_xor(zh, off));
        }
        if (lane == 0) sBB[wv] = make_float2(zl, zh);
    }
    __syncthreads();

    if (wv != 0) return;   // waves 1-7 done; wave 0 runs FPS alone (no more barriers)

    float2 b0 = sBB[0], b1 = sBB[1], b2 = sBB[2], b3 = sBB[3];
    float2 b4 = sBB[4], b5 = sBB[5], b6 = sBB[6], b7 = sBB[7];

    float2v d0[8], d1[8], d2[8], d3[8], d4[8], d5[8], d6[8], d7[8];
#define DINIT(dq) { _Pragma("unroll") for (int u = 0; u < 8; u++) { dq[u].x = 1e10f; dq[u].y = 1e10f; } }
    DINIT(d0) DINIT(d1) DINIT(d2) DINIT(d3) DINIT(d4) DINIT(d5) DINIT(d6) DINIT(d7)
#undef DINIT
    ull k0 = 0, k1 = 0, k2 = 0, k3 = 0, k4 = 0, k5 = 0, k6 = 0, k7 = 0;
    float w0 = 1e30f, w1 = 1e30f, w2 = 1e30f, w3 = 1e30f;
    float w4 = 1e30f, w5 = 1e30f, w6 = 1e30f, w7 = 1e30f;

    float4 c0 = p4[0];
    float cx = c0.x, cy = c0.y, cz = c0.z;
    float* outc = out_xyz + b * Sn * 3;

    for (int s = 0; s < Sn; s++) {
        if (lane == 0) {   // fire-and-forget sample record
            outc[s * 3 + 0] = cx;
            outc[s * 3 + 1] = cy;
            outc[s * 3 + 2] = cz;
        }
        float2v nX, nY, nZ;
        nX.x = -cx; nX.y = -cx;
        nY.x = -cy; nY.y = -cy;
        nZ.x = -cz; nZ.y = -cz;

        slab_step<0>(sP4, b0, cz, nX, nY, nZ, d0, k0, w0, lane);
        slab_step<1>(sP4, b1, cz, nX, nY, nZ, d1, k1, w1, lane);
        slab_step<2>(sP4, b2, cz, nX, nY, nZ, d2, k2, w2, lane);
        slab_step<3>(sP4, b3, cz, nX, nY, nZ, d3, k3, w3, lane);
        slab_step<4>(sP4, b4, cz, nX, nY, nZ, d4, k4, w4, lane);
        slab_step<5>(sP4, b5, cz, nX, nY, nZ, d5, k5, w5, lane);
        slab_step<6>(sP4, b6, cz, nX, nY, nZ, d6, k6, w6, lane);
        slab_step<7>(sP4, b7, cz, nX, nY, nZ, d7, k7, w7, lane);

        ull m01 = (k1 > k0) ? k1 : k0;
        ull m23 = (k3 > k2) ? k3 : k2;
        ull m45 = (k5 > k4) ? k5 : k4;
        ull m67 = (k7 > k6) ? k7 : k6;
        ull m03 = (m23 > m01) ? m23 : m01;
        ull m47 = (m67 > m45) ? m67 : m45;
        ull kk  = (m47 > m03) ? m47 : m03;

        int slot = (int)(kk & 0x1FFFull);   // broadcast LDS fetch
        float4 c4 = sP4[slot];
        cx = c4.x; cy = c4.y; cz = c4.z;
    }
}

// ---------------------------------------------------------------------------
// Ball query (unchanged; exact-decision verified: absmax 0.0).
// ---------------------------------------------------------------------------
__global__ __launch_bounds__(256) void ballq_kernel(const float* __restrict__ ws,
                                                    const float* __restrict__ newxyz,
                                                    int* __restrict__ grp) {
    #pragma clang fp contract(off)
    int t = blockIdx.x * 256 + threadIdx.x;
    int wid = t >> 6;
    int lane = t & 63;
    int b = wid >> 11;
    const float4* p4 = (const float4*)(ws + WS_P4) + b * Nn;

    float nx = newxyz[wid * 3 + 0], ny = newxyz[wid * 3 + 1], nz = newxyz[wid * 3 + 2];
    float a2 = (nx * nx + ny * ny) + nz * nz;

    int total = 0;
    int firstp = 0;
    for (int c = 0; c < Nn / 64; c++) {
        int p = c * 64 + lane;
        float4 v = p4[p];
        float x = v.x, y = v.y, z = v.z;
        float bv = (x * x + y * y) + z * z;
        float dot = __builtin_fmaf(nx, x, 0.0f);
        dot = __builtin_fmaf(ny, y, dot);
        dot = __builtin_fmaf(nz, z, dot);
        float sq = (a2 + bv) - 2.0f * dot;
        bool hit = !(sq > R2c);
        unsigned long long mask = __ballot(hit);
        if (mask) {
            if (total == 0) firstp = c * 64 + (__ffsll(mask) - 1);
            int rank = __popcll(mask & ((1ull << lane) - 1ull));
            int slot = total + rank;
            if (hit && slot < Kn) grp[wid * Kn + slot] = p;
            total += (int)__popcll(mask);
            if (total >= Kn) break;
        }
    }
    if (lane >= total && lane < Kn) grp[wid * Kn + lane] = firstp;
}

// ---------------------------------------------------------------------------
// MFMA MLP (unchanged): one group per block, 256 threads = 4 waves.
// ---------------------------------------------------------------------------
template<int KB, int O>
__device__ __forceinline__ void mfma_layer(const unsigned short* __restrict__ X,
                                           unsigned short* __restrict__ Y,
                                           const unsigned short* __restrict__ wb,
                                           const float* __restrict__ bias,
                                           int lane, int wv) {
    const int Cp = KB * 32;
    const int mt = wv & 1;
    const int mrow = mt * 16 + (lane & 15);
    const int quad = lane >> 4;

    short8 a[KB];
    #pragma unroll
    for (int kb = 0; kb < KB; kb++)
        a[kb] = *(const short8*)&X[mrow * HSTR + kb * 32 + quad * 8];

    for (int nt = (wv >> 1); nt < O / 16; nt += 2) {
        int n0 = nt * 16;
        float bv = bias[n0 + (lane & 15)];
        floatx4 acc = {bv, bv, bv, bv};
        #pragma unroll
        for (int kb = 0; kb < KB; kb++) {
            short8 bf = *(const short8*)&wb[(n0 + (lane & 15)) * Cp + kb * 32 + quad * 8];
            acc = __builtin_amdgcn_mfma_f32_16x16x32_bf16(a[kb], bf, acc, 0, 0, 0);
        }
        #pragma unroll
        for (int r = 0; r < 4; r++) {
            float v = fmaxf(acc[r], 0.f);
            int m = mt * 16 + quad * 4 + r;
            Y[m * HSTR + n0 + (lane & 15)] = f2bf(v);
        }
    }
}

__global__ __launch_bounds__(256) void mlp_kernel(const float* __restrict__ xyz,
                                                  const float* __restrict__ feat,
                                                  const float* __restrict__ ws,
                                                  const int* __restrict__ grp,
                                                  const float* __restrict__ b1,
                                                  const float* __restrict__ b2,
                                                  const float* __restrict__ b3,
                                                  float* __restrict__ out) {
    __shared__ __align__(16) unsigned short hA[32 * HSTR];
    __shared__ __align__(16) unsigned short hB[32 * HSTR];
    __shared__ float mxs[2][256];
    __shared__ int   sIdx[Kn];
    __shared__ float sCent[3];

    int g = blockIdx.x;            // b*S + s
    int b = g >> 11;
    int tid = threadIdx.x;
    int lane = tid & 63, wv = tid >> 6;

    if (tid < Kn) sIdx[tid] = grp[g * Kn + tid];
    if (tid == 0) { sCent[0] = out[g*3]; sCent[1] = out[g*3+1]; sCent[2] = out[g*3+2]; }
    // zero hA (pad cols must be 0 for the K=96 layer)
    {
        short8 z = {0,0,0,0,0,0,0,0};
        for (int i = tid; i < 32 * HSTR / 8; i += 256)
            ((short8*)hA)[i] = z;
    }
    __syncthreads();

    { // stage h0: feats -> cols 0..63 (bf16x8 vector writes), xyz -> 64..66
        int m = tid >> 3, m8 = tid & 7;
        int idx = sIdx[m];
        int base = b * Nn + idx;
        const float4* f4 = (const float4*)(feat + base * 64 + m8 * 8);
        float4 va = f4[0], vb = f4[1];
        short8 pk;
        pk[0] = (short)f2bf(va.x); pk[1] = (short)f2bf(va.y);
        pk[2] = (short)f2bf(va.z); pk[3] = (short)f2bf(va.w);
        pk[4] = (short)f2bf(vb.x); pk[5] = (short)f2bf(vb.y);
        pk[6] = (short)f2bf(vb.z); pk[7] = (short)f2bf(vb.w);
        *(short8*)&hA[m * HSTR + m8 * 8] = pk;
        if (m8 == 0) {
            hA[m * HSTR + 64] = f2bf(xyz[base * 3 + 0] - sCent[0]);
            hA[m * HSTR + 65] = f2bf(xyz[base * 3 + 1] - sCent[1]);
            hA[m * HSTR + 66] = f2bf(xyz[base * 3 + 2] - sCent[2]);
        }
    }
    __syncthreads();

    const unsigned short* wb1 = (const unsigned short*)(ws + WS_WB1);
    const unsigned short* wb2 = (const unsigned short*)(ws + WS_WB2);
    const unsigned short* wb3 = (const unsigned short*)(ws + WS_WB3);

    mfma_layer<3, 64>(hA, hB, wb1, b1, lane, wv);     // 96 -> 64
    __syncthreads();
    mfma_layer<2, 128>(hB, hA, wb2, b2, lane, wv);    // 64 -> 128
    __syncthreads();

    { // L3 (128 -> 256) + fused maxpool
        const int mt = wv & 1;
        const int mrow = mt * 16 + (lane & 15);
        const int quad = lane >> 4;
        short8 a[4];
        #pragma unroll
        for (int kb = 0; kb < 4; kb++)
            a[kb] = *(const short8*)&hA[mrow * HSTR + kb * 32 + quad * 8];
        for (int nt = (wv >> 1); nt < 16; nt += 2) {
            int n0 = nt * 16;
            float bv = b3[n0 + (lane & 15)];
            floatx4 acc = {bv, bv, bv, bv};
            #pragma unroll
            for (int kb = 0; kb < 4; kb++) {
                short8 bf = *(const short8*)&wb3[(n0 + (lane & 15)) * 128 + kb * 32 + quad * 8];
                acc = __builtin_amdgcn_mfma_f32_16x16x32_bf16(a[kb], bf, acc, 0, 0, 0);
            }
            float pm = fmaxf(fmaxf(fmaxf(acc[0], acc[1]), fmaxf(acc[2], acc[3])), 0.f);
            pm = fmaxf(pm, __shfl_xor(pm, 16));   // reduce across the 4 quads
            pm = fmaxf(pm, __shfl_xor(pm, 32));
            if (lane < 16) mxs[mt][n0 + lane] = pm;
        }
    }
    __syncthreads();

    out[OUT_XYZ + g * 256 + tid] = fmaxf(mxs[0][tid], mxs[1][tid]);
}

// ---------------------------------------------------------------------------
extern "C" void kernel_launch(void* const* d_in, const int* in_sizes, int n_in,
                              void* d_out, int out_size, void* d_ws, size_t ws_size,
                              hipStream_t stream) {
    const float* xyz  = (const float*)d_in[0];
    const float* feat = (const float*)d_in[1];
    const float* W1   = (const float*)d_in[2];
    const float* b1   = (const float*)d_in[3];
    const float* W2   = (const float*)d_in[4];
    const float* b2   = (const float*)d_in[5];
    const float* W3   = (const float*)d_in[6];
    const float* b3   = (const float*)d_in[7];
    float* out = (float*)d_out;
    float* ws  = (float*)d_ws;
    int*   grp = (int*)d_ws + WS_GRP;

    hipLaunchKernelGGL(prep_kernel, dim3(312), dim3(256), 0, stream, xyz, W1, W2, W3, ws);
    hipLaunchKernelGGL(fps_kernel, dim3(Bn), dim3(512), 0, stream, ws, out);
    hipLaunchKernelGGL(ballq_kernel, dim3(Bn * Sn / 4), dim3(256), 0, stream, ws, out, grp);
    hipLaunchKernelGGL(mlp_kernel, dim3(Bn * Sn), dim3(256), 0, stream,
                       xyz, feat, ws, grp, b1, b2, b3, out);
}

// Round 7
// 2372.669 us; speedup vs baseline: 2.6370x; 2.6370x over previous
//
#include <hip/hip_runtime.h>

// Problem constants
#define Bn 4
#define Nn 8192
#define Dn 64
#define Sn 2048
#define Kn 32
#define R2c 0.04f          // f32(0.2*0.2)
#define OUT_XYZ (Bn*Sn*3)  // 24576 floats of new_xyz, then feats

// Workspace layout (units = 4-byte elements)
#define WS_P4  0            // [B*N] float4 {x,y,z,0}
#define WS_WB1 131072       // bf16 W1' [64][96]  (feat-first permute, zero pad)
#define WS_WB2 134144       // bf16 W2  [128][64]
#define WS_WB3 138240       // bf16 W3  [256][128]
#define WS_GRP 154624       // int grp_idx [B*S][K]

#define HSTR 136            // bf16 LDS row stride (128 max C + 8 pad)

typedef __attribute__((ext_vector_type(8))) short short8;
typedef __attribute__((ext_vector_type(4))) float floatx4;
typedef __attribute__((ext_vector_type(2))) float float2v;
typedef unsigned long long ull;

// float -> bf16 (RNE) without relying on header APIs
__device__ __forceinline__ unsigned short f2bf(float f) {
    unsigned u = __float_as_uint(f);
    return (unsigned short)((u + 0x7FFFu + ((u >> 16) & 1u)) >> 16);
}

// ---------------------------------------------------------------------------
// Prep: xyz -> float4 array; weights -> bf16 [O][Cp] row-major.
// ---------------------------------------------------------------------------
__global__ __launch_bounds__(256) void prep_kernel(const float* __restrict__ xyz,
                                                   const float* __restrict__ W1,
                                                   const float* __restrict__ W2,
                                                   const float* __restrict__ W3,
                                                   float* __restrict__ ws) {
    int id = blockIdx.x * 256 + threadIdx.x;
    if (id < Bn * Nn) {
        float4* p4 = (float4*)(ws + WS_P4);
        p4[id] = make_float4(xyz[id * 3 + 0], xyz[id * 3 + 1], xyz[id * 3 + 2], 0.f);
    }
    int i1 = id - Bn * Nn;
    if (i1 >= 0 && i1 < 64 * 96) {
        int o = i1 / 96, c = i1 % 96;
        float v = (c < 64) ? W1[o * 67 + 3 + c] : (c < 67 ? W1[o * 67 + (c - 64)] : 0.f);
        ((unsigned short*)(ws + WS_WB1))[i1] = f2bf(v);
    }
    int i2 = i1 - 64 * 96;
    if (i2 >= 0 && i2 < 128 * 64)
        ((unsigned short*)(ws + WS_WB2))[i2] = f2bf(W2[i2]);
    int i3 = i2 - 128 * 64;
    if (i3 >= 0 && i3 < 256 * 128)
        ((unsigned short*)(ws + WS_WB3))[i3] = f2bf(W3[i3]);
}

// Fused wave-64 lexicographic max of 64-bit keys (hi=dist bits, lo=payload).
// One DPP ladder; 0-injection from bound_ctrl can never win. Result
// broadcast via 2 readlanes from lane 63 (SGPR-uniform).
__device__ __forceinline__ ull wave_kmax_dpp(ull k) {
    unsigned lo = (unsigned)k, hi = (unsigned)(k >> 32);
#define KRUNG(ctl)                                                                          \
    {                                                                                       \
        unsigned tlo = (unsigned)__builtin_amdgcn_update_dpp(0, (int)lo, ctl, 0xf, 0xf, true); \
        unsigned thi = (unsigned)__builtin_amdgcn_update_dpp(0, (int)hi, ctl, 0xf, 0xf, true); \
        ull t = ((ull)thi << 32) | tlo;                                                     \
        ull c = ((ull)hi << 32) | lo;                                                       \
        if (t > c) { hi = thi; lo = tlo; }                                                  \
    }
    KRUNG(0x111) KRUNG(0x112) KRUNG(0x114) KRUNG(0x118) KRUNG(0x142) KRUNG(0x143)
#undef KRUNG
    hi = (unsigned)__builtin_amdgcn_readlane((int)hi, 63);
    lo = (unsigned)__builtin_amdgcn_readlane((int)lo, 63);
    return ((ull)hi << 32) | lo;
}

// ---------------------------------------------------------------------------
// Farthest point sampling — LDS-dist, 16-chunk round-robin version.
//
// Points z-sorted into LDS sP4[8192] = (x,y,z,DIST); origIdx in u16 side
// table. 16 chunks of 512 consecutive slots; chunk c owned by wave c&7
// (consecutive active chunks -> distinct waves, free parallel distribution).
// Per step, each wave tests its 2 chunks' cached z-bboxes against the
// chunks' cached wmax (conservative skip, bit-exact as R4/R5: dists only
// decrease, so a skipped chunk's min(dist,d)=dist for every point and its
// cached key stays valid). Active chunks: 8 pts/lane read-modify-write
// through LDS (b128 read, pk math, b32 write of the dist word), lane-tie
// recovery, fused u64 DPP ladder. Cached (key,wmax) per chunk live in the
// owner wave's registers; parity-double-buffered 16-key LDS exchange, ONE
// barrier/step; all waves redundantly tree the 16 keys + broadcast-fetch
// the winner's coords from sP4 (x/y/z words are never written after sort;
// concurrent w-word writes don't overlap them).
//
// vs R5 (1532 us): halves the active-chunk update (512 vs 1024 pts),
// finer skip granularity (0.0625 vs 0.125 z), no per-point registers
// (R6's spill disaster avoided); same verified FP ops and tie-break.
// ---------------------------------------------------------------------------
__global__ __launch_bounds__(512, 2) void fps_kernel(const float* __restrict__ ws,
                                                     float* __restrict__ out_xyz) {
    #pragma clang fp contract(off)
    const int b = blockIdx.x;
    const int tid = threadIdx.x;
    const int lane = tid & 63;
    const int wv = tid >> 6;
    const float4* p4 = (const float4*)(ws + WS_P4) + b * Nn;

    __shared__ __align__(16) float4 sP4[Nn];            // 128 KB (x,y,z,dist)
    __shared__ unsigned short sOrig[Nn];                // 16 KB orig indices
    __shared__ ull sKey[2][16];                         // parity-dbuf chunk keys
    __shared__ int sH[256];                             // histogram
    __shared__ int sC[256];                             // cursors

    // ---- load original points (coalesced) ----
    float4 t4[16];
    #pragma unroll
    for (int j = 0; j < 16; j++) t4[j] = p4[j * 512 + tid];

    // ---- histogram over 256 z-bins ----
    for (int i = tid; i < 256; i += 512) sH[i] = 0;
    __syncthreads();
    int slt[16];
    #pragma unroll
    for (int j = 0; j < 16; j++) {
        int bin = (int)(t4[j].z * 256.0f);
        bin = bin < 0 ? 0 : (bin > 255 ? 255 : bin);
        slt[j] = bin;
        atomicAdd(&sH[bin], 1);
    }
    __syncthreads();

    // ---- exclusive scan of 256 bins (wave 0, 4 bins/lane) ----
    if (tid < 64) {
        int b4 = tid * 4;
        int h0 = sH[b4], h1 = sH[b4 + 1], h2 = sH[b4 + 2], h3 = sH[b4 + 3];
        int sum = h0 + h1 + h2 + h3;
        int inc = sum;
        #pragma unroll
        for (int off = 1; off < 64; off <<= 1) {
            int o = __shfl_up(inc, off);
            if (tid >= off) inc += o;
        }
        int exc = inc - sum;
        sC[b4]     = exc;
        sC[b4 + 1] = exc + h0;
        sC[b4 + 2] = exc + h0 + h1;
        sC[b4 + 3] = exc + h0 + h1 + h2;
    }
    __syncthreads();

    // ---- claim unique sorted slots, scatter (coords + dist init + orig) ----
    #pragma unroll
    for (int j = 0; j < 16; j++)
        slt[j] = atomicAdd(&sC[slt[j]], 1);
    #pragma unroll
    for (int j = 0; j < 16; j++) {
        sP4[slt[j]] = make_float4(t4[j].x, t4[j].y, t4[j].z, 1e10f);
        sOrig[slt[j]] = (unsigned short)(j * 512 + tid);
    }
    __syncthreads();

    // ---- own chunks' z-bboxes (exact butterflies), kept in registers ----
    const int c0 = wv, c1 = wv + 8;
    float bl0, bh0, bl1, bh1;
    {
        float zl = 1e30f, zh = -1e30f;
        #pragma unroll
        for (int u = 0; u < 8; u++) {
            float z = sP4[c0 * 512 + u * 64 + lane].z;
            zl = fminf(zl, z); zh = fmaxf(zh, z);
        }
        #pragma unroll
        for (int off = 1; off < 64; off <<= 1) {
            zl = fminf(zl, __shfl_xor(zl, off));
            zh = fmaxf(zh, __shfl_xor(zh, off));
        }
        bl0 = zl; bh0 = zh;
        zl = 1e30f; zh = -1e30f;
        #pragma unroll
        for (int u = 0; u < 8; u++) {
            float z = sP4[c1 * 512 + u * 64 + lane].z;
            zl = fminf(zl, z); zh = fmaxf(zh, z);
        }
        #pragma unroll
        for (int off = 1; off < 64; off <<= 1) {
            zl = fminf(zl, __shfl_xor(zl, off));
            zh = fmaxf(zh, __shfl_xor(zh, off));
        }
        bl1 = zl; bh1 = zh;
    }

    // cached per-chunk keys (owner registers); wmax=inf forces step-0 update
    ull k0r = 0, k1r = 0;
    float w0r = 1e30f, w1r = 1e30f;

    float4 cc0 = p4[0];
    float cx = cc0.x, cy = cc0.y, cz = cc0.z;
    float* outc = out_xyz + b * Sn * 3;
    float* sP4w = (float*)sP4;   // scalar view for dist-word writes

#define CHUNK_STEP(C, BL, BH, KR, WR)                                              \
    {                                                                              \
        float dzb = fmaxf(fmaxf((BL) - cz, cz - (BH)), 0.0f);                      \
        if (dzb * dzb * 0.999999f < (WR)) {                                        \
            float2v nX, nY, nZ;                                                    \
            nX.x = -cx; nX.y = -cx;                                                \
            nY.x = -cy; nY.y = -cy;                                                \
            nZ.x = -cz; nZ.y = -cz;                                                \
            float lv = -1.0f;                                                      \
            float dm[8]; unsigned lo_[8];                                          \
            _Pragma("unroll")                                                      \
            for (int u = 0; u < 4; u++) {                                          \
                int a0 = (C) * 512 + (2 * u) * 64 + lane;                          \
                int a1 = a0 + 64;                                                  \
                float4 va = sP4[a0];                                               \
                float4 vb = sP4[a1];                                               \
                float2v px, py, pz;                                                \
                px.x = va.x; px.y = vb.x;                                          \
                py.x = va.y; py.y = vb.y;                                          \
                pz.x = va.z; pz.y = vb.z;                                          \
                float2v dx, dy, dz_, xx, yy, zz, s1, d2;                           \
                asm("v_pk_add_f32 %0, %1, %2" : "=v"(dx) : "v"(px), "v"(nX));      \
                asm("v_pk_add_f32 %0, %1, %2" : "=v"(dy) : "v"(py), "v"(nY));      \
                asm("v_pk_add_f32 %0, %1, %2" : "=v"(dz_) : "v"(pz), "v"(nZ));     \
                asm("v_pk_mul_f32 %0, %1, %1" : "=v"(xx) : "v"(dx));               \
                asm("v_pk_mul_f32 %0, %1, %1" : "=v"(yy) : "v"(dy));               \
                asm("v_pk_mul_f32 %0, %1, %1" : "=v"(zz) : "v"(dz_));              \
                asm("v_pk_add_f32 %0, %1, %2" : "=v"(s1) : "v"(xx), "v"(yy));      \
                asm("v_pk_add_f32 %0, %1, %2" : "=v"(d2) : "v"(s1), "v"(zz));      \
                float ma = fminf(va.w, d2.x);                                      \
                float mb = fminf(vb.w, d2.y);                                      \
                sP4w[a0 * 4 + 3] = ma;                                             \
                sP4w[a1 * 4 + 3] = mb;                                             \
                dm[2 * u] = ma; dm[2 * u + 1] = mb;                                \
                lo_[2 * u]     = ((8191u - (unsigned)sOrig[a0]) << 13) | (unsigned)a0; \
                lo_[2 * u + 1] = ((8191u - (unsigned)sOrig[a1]) << 13) | (unsigned)a1; \
                lv = fmaxf(fmaxf(lv, ma), mb);                                     \
            }                                                                      \
            unsigned cnd[8];                                                       \
            _Pragma("unroll")                                                      \
            for (int u = 0; u < 8; u++)                                            \
                cnd[u] = (dm[u] == lv) ? lo_[u] : 0u;                              \
            _Pragma("unroll")                                                      \
            for (int st = 1; st < 8; st <<= 1)                                     \
                _Pragma("unroll")                                                  \
                for (int i = 0; i < 8; i += 2 * st)                                \
                    cnd[i] = (cnd[i + st] > cnd[i]) ? cnd[i + st] : cnd[i];        \
            ull kk_ = ((ull)__float_as_uint(lv) << 32) | (ull)cnd[0];              \
            KR = wave_kmax_dpp(kk_);                                               \
            WR = __uint_as_float((unsigned)((KR) >> 32));                          \
        }                                                                          \
    }

    for (int s = 0; s < Sn; s++) {
        const int par = s & 1;
        if (tid == 0) {    // fire-and-forget sample record
            outc[s * 3 + 0] = cx;
            outc[s * 3 + 1] = cy;
            outc[s * 3 + 2] = cz;
        }

        CHUNK_STEP(c0, bl0, bh0, k0r, w0r)
        CHUNK_STEP(c1, bl1, bh1, k1r, w1r)

        if (lane == 0) {
            sKey[par][c0] = k0r;
            sKey[par][c1] = k1r;
        }
        __syncthreads();

        const ull* kp = sKey[par];
        ull t0 = (kp[1]  > kp[0])  ? kp[1]  : kp[0];
        ull t1 = (kp[3]  > kp[2])  ? kp[3]  : kp[2];
        ull t2 = (kp[5]  > kp[4])  ? kp[5]  : kp[4];
        ull t3 = (kp[7]  > kp[6])  ? kp[7]  : kp[6];
        ull t4_ = (kp[9]  > kp[8])  ? kp[9]  : kp[8];
        ull t5 = (kp[11] > kp[10]) ? kp[11] : kp[10];
        ull t6 = (kp[13] > kp[12]) ? kp[13] : kp[12];
        ull t7 = (kp[15] > kp[14]) ? kp[15] : kp[14];
        t0 = (t1 > t0) ? t1 : t0;
        t2 = (t3 > t2) ? t3 : t2;
        t4_ = (t5 > t4_) ? t5 : t4_;
        t6 = (t7 > t6) ? t7 : t6;
        t0 = (t2 > t0) ? t2 : t0;
        t4_ = (t6 > t4_) ? t6 : t4_;
        ull kk = (t4_ > t0) ? t4_ : t0;

        int slot = (int)(kk & 0x1FFFull);   // broadcast LDS fetch (x,y,z only)
        float4 c4 = sP4[slot];
        cx = c4.x; cy = c4.y; cz = c4.z;
    }
#undef CHUNK_STEP
}

// ---------------------------------------------------------------------------
// Ball query (unchanged; exact-decision verified: absmax 0.0).
// ---------------------------------------------------------------------------
__global__ __launch_bounds__(256) void ballq_kernel(const float* __restrict__ ws,
                                                    const float* __restrict__ newxyz,
                                                    int* __restrict__ grp) {
    #pragma clang fp contract(off)
    int t = blockIdx.x * 256 + threadIdx.x;
    int wid = t >> 6;
    int lane = t & 63;
    int b = wid >> 11;
    const float4* p4 = (const float4*)(ws + WS_P4) + b * Nn;

    float nx = newxyz[wid * 3 + 0], ny = newxyz[wid * 3 + 1], nz = newxyz[wid * 3 + 2];
    float a2 = (nx * nx + ny * ny) + nz * nz;

    int total = 0;
    int firstp = 0;
    for (int c = 0; c < Nn / 64; c++) {
        int p = c * 64 + lane;
        float4 v = p4[p];
        float x = v.x, y = v.y, z = v.z;
        float bv = (x * x + y * y) + z * z;
        float dot = __builtin_fmaf(nx, x, 0.0f);
        dot = __builtin_fmaf(ny, y, dot);
        dot = __builtin_fmaf(nz, z, dot);
        float sq = (a2 + bv) - 2.0f * dot;
        bool hit = !(sq > R2c);
        unsigned long long mask = __ballot(hit);
        if (mask) {
            if (total == 0) firstp = c * 64 + (__ffsll(mask) - 1);
            int rank = __popcll(mask & ((1ull << lane) - 1ull));
            int slot = total + rank;
            if (hit && slot < Kn) grp[wid * Kn + slot] = p;
            total += (int)__popcll(mask);
            if (total >= Kn) break;
        }
    }
    if (lane >= total && lane < Kn) grp[wid * Kn + lane] = firstp;
}

// ---------------------------------------------------------------------------
// MFMA MLP (unchanged): one group per block, 256 threads = 4 waves.
// ---------------------------------------------------------------------------
template<int KB, int O>
__device__ __forceinline__ void mfma_layer(const unsigned short* __restrict__ X,
                                           unsigned short* __restrict__ Y,
                                           const unsigned short* __restrict__ wb,
                                           const float* __restrict__ bias,
                                           int lane, int wv) {
    const int Cp = KB * 32;
    const int mt = wv & 1;
    const int mrow = mt * 16 + (lane & 15);
    const int quad = lane >> 4;

    short8 a[KB];
    #pragma unroll
    for (int kb = 0; kb < KB; kb++)
        a[kb] = *(const short8*)&X[mrow * HSTR + kb * 32 + quad * 8];

    for (int nt = (wv >> 1); nt < O / 16; nt += 2) {
        int n0 = nt * 16;
        float bv = bias[n0 + (lane & 15)];
        floatx4 acc = {bv, bv, bv, bv};
        #pragma unroll
        for (int kb = 0; kb < KB; kb++) {
            short8 bf = *(const short8*)&wb[(n0 + (lane & 15)) * Cp + kb * 32 + quad * 8];
            acc = __builtin_amdgcn_mfma_f32_16x16x32_bf16(a[kb], bf, acc, 0, 0, 0);
        }
        #pragma unroll
        for (int r = 0; r < 4; r++) {
            float v = fmaxf(acc[r], 0.f);
            int m = mt * 16 + quad * 4 + r;
            Y[m * HSTR + n0 + (lane & 15)] = f2bf(v);
        }
    }
}

__global__ __launch_bounds__(256) void mlp_kernel(const float* __restrict__ xyz,
                                                  const float* __restrict__ feat,
                                                  const float* __restrict__ ws,
                                                  const int* __restrict__ grp,
                                                  const float* __restrict__ b1,
                                                  const float* __restrict__ b2,
                                                  const float* __restrict__ b3,
                                                  float* __restrict__ out) {
    __shared__ __align__(16) unsigned short hA[32 * HSTR];
    __shared__ __align__(16) unsigned short hB[32 * HSTR];
    __shared__ float mxs[2][256];
    __shared__ int   sIdx[Kn];
    __shared__ float sCent[3];

    int g = blockIdx.x;            // b*S + s
    int b = g >> 11;
    int tid = threadIdx.x;
    int lane = tid & 63, wv = tid >> 6;

    if (tid < Kn) sIdx[tid] = grp[g * Kn + tid];
    if (tid == 0) { sCent[0] = out[g*3]; sCent[1] = out[g*3+1]; sCent[2] = out[g*3+2]; }
    // zero hA (pad cols must be 0 for the K=96 layer)
    {
        short8 z = {0,0,0,0,0,0,0,0};
        for (int i = tid; i < 32 * HSTR / 8; i += 256)
            ((short8*)hA)[i] = z;
    }
    __syncthreads();

    { // stage h0: feats -> cols 0..63 (bf16x8 vector writes), xyz -> 64..66
        int m = tid >> 3, m8 = tid & 7;
        int idx = sIdx[m];
        int base = b * Nn + idx;
        const float4* f4 = (const float4*)(feat + base * 64 + m8 * 8);
        float4 va = f4[0], vb = f4[1];
        short8 pk;
        pk[0] = (short)f2bf(va.x); pk[1] = (short)f2bf(va.y);
        pk[2] = (short)f2bf(va.z); pk[3] = (short)f2bf(va.w);
        pk[4] = (short)f2bf(vb.x); pk[5] = (short)f2bf(vb.y);
        pk[6] = (short)f2bf(vb.z); pk[7] = (short)f2bf(vb.w);
        *(short8*)&hA[m * HSTR + m8 * 8] = pk;
        if (m8 == 0) {
            hA[m * HSTR + 64] = f2bf(xyz[base * 3 + 0] - sCent[0]);
            hA[m * HSTR + 65] = f2bf(xyz[base * 3 + 1] - sCent[1]);
            hA[m * HSTR + 66] = f2bf(xyz[base * 3 + 2] - sCent[2]);
        }
    }
    __syncthreads();

    const unsigned short* wb1 = (const unsigned short*)(ws + WS_WB1);
    const unsigned short* wb2 = (const unsigned short*)(ws + WS_WB2);
    const unsigned short* wb3 = (const unsigned short*)(ws + WS_WB3);

    mfma_layer<3, 64>(hA, hB, wb1, b1, lane, wv);     // 96 -> 64
    __syncthreads();
    mfma_layer<2, 128>(hB, hA, wb2, b2, lane, wv);    // 64 -> 128
    __syncthreads();

    { // L3 (128 -> 256) + fused maxpool
        const int mt = wv & 1;
        const int mrow = mt * 16 + (lane & 15);
        const int quad = lane >> 4;
        short8 a[4];
        #pragma unroll
        for (int kb = 0; kb < 4; kb++)
            a[kb] = *(const short8*)&hA[mrow * HSTR + kb * 32 + quad * 8];
        for (int nt = (wv >> 1); nt < 16; nt += 2) {
            int n0 = nt * 16;
            float bv = b3[n0 + (lane & 15)];
            floatx4 acc = {bv, bv, bv, bv};
            #pragma unroll
            for (int kb = 0; kb < 4; kb++) {
                short8 bf = *(const short8*)&wb3[(n0 + (lane & 15)) * 128 + kb * 32 + quad * 8];
                acc = __builtin_amdgcn_mfma_f32_16x16x32_bf16(a[kb], bf, acc, 0, 0, 0);
            }
            float pm = fmaxf(fmaxf(fmaxf(acc[0], acc[1]), fmaxf(acc[2], acc[3])), 0.f);
            pm = fmaxf(pm, __shfl_xor(pm, 16));   // reduce across the 4 quads
            pm = fmaxf(pm, __shfl_xor(pm, 32));
            if (lane < 16) mxs[mt][n0 + lane] = pm;
        }
    }
    __syncthreads();

    out[OUT_XYZ + g * 256 + tid] = fmaxf(mxs[0][tid], mxs[1][tid]);
}

// ---------------------------------------------------------------------------
extern "C" void kernel_launch(void* const* d_in, const int* in_sizes, int n_in,
                              void* d_out, int out_size, void* d_ws, size_t ws_size,
                              hipStream_t stream) {
    const float* xyz  = (const float*)d_in[0];
    const float* feat = (const float*)d_in[1];
    const float* W1   = (const float*)d_in[2];
    const float* b1   = (const float*)d_in[3];
    const float* W2   = (const float*)d_in[4];
    const float* b2   = (const float*)d_in[5];
    const float* W3   = (const float*)d_in[6];
    const float* b3   = (const float*)d_in[7];
    float* out = (float*)d_out;
    float* ws  = (float*)d_ws;
    int*   grp = (int*)d_ws + WS_GRP;

    hipLaunchKernelGGL(prep_kernel, dim3(312), dim3(256), 0, stream, xyz, W1, W2, W3, ws);
    hipLaunchKernelGGL(fps_kernel, dim3(Bn), dim3(512), 0, stream, ws, out);
    hipLaunchKernelGGL(ballq_kernel, dim3(Bn * Sn / 4), dim3(256), 0, stream, ws, out, grp);
    hipLaunchKernelGGL(mlp_kernel, dim3(Bn * Sn), dim3(256), 0, stream,
                       xyz, feat, ws, grp, b1, b2, b3, out);
}

// Round 8
// 1773.892 us; speedup vs baseline: 3.5271x; 1.3376x over previous
//
#include <hip/hip_runtime.h>

// Problem constants
#define Bn 4
#define Nn 8192
#define Dn 64
#define Sn 2048
#define Kn 32
#define R2c 0.04f          // f32(0.2*0.2)
#define OUT_XYZ (Bn*Sn*3)  // 24576 floats of new_xyz, then feats

// Workspace layout (units = 4-byte elements)
#define WS_P4  0            // [B*N] float4 {x,y,z,0}
#define WS_WB1 131072       // bf16 W1' [64][96]  (feat-first permute, zero pad)
#define WS_WB2 134144       // bf16 W2  [128][64]
#define WS_WB3 138240       // bf16 W3  [256][128]
#define WS_GRP 154624       // int grp_idx [B*S][K]

#define HSTR 136            // bf16 LDS row stride (128 max C + 8 pad)

typedef __attribute__((ext_vector_type(8))) short short8;
typedef __attribute__((ext_vector_type(4))) float floatx4;
typedef __attribute__((ext_vector_type(2))) float float2v;
typedef unsigned long long ull;

// float -> bf16 (RNE) without relying on header APIs
__device__ __forceinline__ unsigned short f2bf(float f) {
    unsigned u = __float_as_uint(f);
    return (unsigned short)((u + 0x7FFFu + ((u >> 16) & 1u)) >> 16);
}

// ---------------------------------------------------------------------------
// Prep: xyz -> float4 array; weights -> bf16 [O][Cp] row-major.
// ---------------------------------------------------------------------------
__global__ __launch_bounds__(256) void prep_kernel(const float* __restrict__ xyz,
                                                   const float* __restrict__ W1,
                                                   const float* __restrict__ W2,
                                                   const float* __restrict__ W3,
                                                   float* __restrict__ ws) {
    int id = blockIdx.x * 256 + threadIdx.x;
    if (id < Bn * Nn) {
        float4* p4 = (float4*)(ws + WS_P4);
        p4[id] = make_float4(xyz[id * 3 + 0], xyz[id * 3 + 1], xyz[id * 3 + 2], 0.f);
    }
    int i1 = id - Bn * Nn;
    if (i1 >= 0 && i1 < 64 * 96) {
        int o = i1 / 96, c = i1 % 96;
        float v = (c < 64) ? W1[o * 67 + 3 + c] : (c < 67 ? W1[o * 67 + (c - 64)] : 0.f);
        ((unsigned short*)(ws + WS_WB1))[i1] = f2bf(v);
    }
    int i2 = i1 - 64 * 96;
    if (i2 >= 0 && i2 < 128 * 64)
        ((unsigned short*)(ws + WS_WB2))[i2] = f2bf(W2[i2]);
    int i3 = i2 - 128 * 64;
    if (i3 >= 0 && i3 < 256 * 128)
        ((unsigned short*)(ws + WS_WB3))[i3] = f2bf(W3[i3]);
}

// Fused wave-64 lexicographic max of 64-bit keys (hi=dist bits, lo=payload).
// One DPP ladder; 0-injection from bound_ctrl can never win. Result
// broadcast via 2 readlanes from lane 63 (SGPR-uniform).
__device__ __forceinline__ ull wave_kmax_dpp(ull k) {
    unsigned lo = (unsigned)k, hi = (unsigned)(k >> 32);
#define KRUNG(ctl)                                                                          \
    {                                                                                       \
        unsigned tlo = (unsigned)__builtin_amdgcn_update_dpp(0, (int)lo, ctl, 0xf, 0xf, true); \
        unsigned thi = (unsigned)__builtin_amdgcn_update_dpp(0, (int)hi, ctl, 0xf, 0xf, true); \
        ull t = ((ull)thi << 32) | tlo;                                                     \
        ull c = ((ull)hi << 32) | lo;                                                       \
        if (t > c) { hi = thi; lo = tlo; }                                                  \
    }
    KRUNG(0x111) KRUNG(0x112) KRUNG(0x114) KRUNG(0x118) KRUNG(0x142) KRUNG(0x143)
#undef KRUNG
    hi = (unsigned)__builtin_amdgcn_readlane((int)hi, 63);
    lo = (unsigned)__builtin_amdgcn_readlane((int)lo, 63);
    return ((ull)hi << 32) | lo;
}

// ---------------------------------------------------------------------------
// Farthest point sampling — R5 structure (best: 1532us) + barrier-drain fix.
//
// R5 unchanged: z-sort into 128KB LDS table sP4 (x,y,z,origIdx); wave w owns
// sorted slots [w*1024,(w+1)*1024) in REGISTERS (R7 proved LDS dist writes
// = 8-way bank-conflict disaster); conservative per-slab z-bbox skip
// (bit-exact); fused u64 key ladder (max dist, then min origIdx); parity-
// double-buffered key exchange, ONE barrier/step; broadcast LDS winner fetch.
//
// THE FIX vs R5: R5 recorded each step's centroid with a GLOBAL store
// inside the loop. The compiler emits s_waitcnt vmcnt(0) before s_barrier
// (HIP __syncthreads semantics), so wave 0 drained its HBM store (~400-600
// cyc) EVERY STEP and gated all 8 waves at the barrier — the ~1000 cyc/step
// unexplained in R5's model. Centroid record now goes to LDS sHist (lgkm
// only, ~free at the barrier); one coalesced dump to global after the loop.
// LDS total ~158KB < 160KB.
// ---------------------------------------------------------------------------
__global__ __launch_bounds__(512, 2) void fps_kernel(const float* __restrict__ ws,
                                                     float* __restrict__ out_xyz) {
    #pragma clang fp contract(off)
    const int b = blockIdx.x;
    const int tid = threadIdx.x;
    const int lane = tid & 63;
    const int wv = tid >> 6;
    const float4* p4 = (const float4*)(ws + WS_P4) + b * Nn;

    __shared__ __align__(16) float4 sP4[Nn];   // 128 KB sorted point table
    __shared__ float sHist[Sn * 3];            // 24 KB per-step centroid record
    __shared__ ull sKey[2][8];
    __shared__ int sH[256];                    // histogram
    __shared__ int sC[256];                    // cursors (exclusive starts)

    // ---- load original points (coalesced) ----
    float4 t4[16];
    #pragma unroll
    for (int j = 0; j < 16; j++) t4[j] = p4[j * 512 + tid];

    // ---- histogram over 256 z-bins ----
    for (int i = tid; i < 256; i += 512) sH[i] = 0;
    __syncthreads();
    int slt[16];
    #pragma unroll
    for (int j = 0; j < 16; j++) {
        int bin = (int)(t4[j].z * 256.0f);
        bin = bin < 0 ? 0 : (bin > 255 ? 255 : bin);
        slt[j] = bin;
        atomicAdd(&sH[bin], 1);
    }
    __syncthreads();

    // ---- exclusive scan of 256 bins (wave 0, 4 bins/lane) ----
    if (tid < 64) {
        int b4 = tid * 4;
        int h0 = sH[b4], h1 = sH[b4 + 1], h2 = sH[b4 + 2], h3 = sH[b4 + 3];
        int sum = h0 + h1 + h2 + h3;
        int inc = sum;
        #pragma unroll
        for (int off = 1; off < 64; off <<= 1) {
            int o = __shfl_up(inc, off);
            if (tid >= off) inc += o;
        }
        int exc = inc - sum;
        sC[b4]     = exc;
        sC[b4 + 1] = exc + h0;
        sC[b4 + 2] = exc + h0 + h1;
        sC[b4 + 3] = exc + h0 + h1 + h2;
    }
    __syncthreads();

    // ---- claim unique sorted slots, scatter into the table ----
    #pragma unroll
    for (int j = 0; j < 16; j++)
        slt[j] = atomicAdd(&sC[slt[j]], 1);
    #pragma unroll
    for (int j = 0; j < 16; j++)
        sP4[slt[j]] = make_float4(t4[j].x, t4[j].y, t4[j].z,
                                  __int_as_float(j * 512 + tid));
    __syncthreads();

    // ---- slab read: wave wv owns slots [wv*1024, wv*1024+1024) ----
    float2v pX[8], pY[8], pZ[8], dI[8];
    unsigned loA[8], loB[8];
    const int sbase = wv * 1024 + lane * 2;
    #pragma unroll
    for (int u = 0; u < 8; u++) {
        int sa = sbase + u * 128;
        float4 va = sP4[sa];
        float4 vb = sP4[sa + 1];
        pX[u].x = va.x; pX[u].y = vb.x;
        pY[u].x = va.y; pY[u].y = vb.y;
        pZ[u].x = va.z; pZ[u].y = vb.z;
        unsigned ogA = (unsigned)__float_as_int(va.w);
        unsigned ogB = (unsigned)__float_as_int(vb.w);
        loA[u] = ((8191u - ogA) << 13) | (unsigned)sa;
        loB[u] = ((8191u - ogB) << 13) | (unsigned)(sa + 1);
        dI[u].x = 1e10f; dI[u].y = 1e10f;
    }
    #pragma unroll
    for (int u = 0; u < 8; u++)
        asm volatile("" : "+v"(pX[u]), "+v"(pY[u]), "+v"(pZ[u]));

    // ---- wave z-bbox (exact min/max butterfly, one time) ----
    float zl = fminf(pZ[0].x, pZ[0].y);
    float zh = fmaxf(pZ[0].x, pZ[0].y);
    #pragma unroll
    for (int u = 1; u < 8; u++) {
        zl = fminf(zl, fminf(pZ[u].x, pZ[u].y));
        zh = fmaxf(zh, fmaxf(pZ[u].x, pZ[u].y));
    }
    #pragma unroll
    for (int off = 1; off < 64; off <<= 1) {
        zl = fminf(zl, __shfl_xor(zl, off));
        zh = fmaxf(zh, __shfl_xor(zh, off));
    }

    // ---- main FPS loop ----
    float4 c0 = p4[0];
    float cx = c0.x, cy = c0.y, cz = c0.z;
    float wmaxC = 1e30f;     // cached wave max dist (forces first step active)
    ull bestK = 0;           // cached wave best key

    for (int s = 0; s < Sn; s++) {
        const int par = s & 1;
        if (tid == 0) {       // LDS record: no vmcnt at the barrier
            sHist[s * 3 + 0] = cx;
            sHist[s * 3 + 1] = cy;
            sHist[s * 3 + 2] = cz;
        }

        // conservative slab distance: skip only if provably no dist changes
        float dzb = fmaxf(fmaxf(zl - cz, cz - zh), 0.0f);
        float dz2s = dzb * dzb * 0.999999f;
        if (dz2s < wmaxC) {   // wave-uniform branch
            float nxs = -cx, nys = -cy, nzs = -cz;
            float2v nX, nY, nZ;
            nX.x = nxs; nX.y = nxs;
            nY.x = nys; nY.y = nys;
            nZ.x = nzs; nZ.y = nzs;

            float lv = -1.0f;
            #pragma unroll
            for (int u = 0; u < 8; u++) {
                float2v dx, dy, dz_, xx, yy, zz, s1, d2;
                asm("v_pk_add_f32 %0, %1, %2" : "=v"(dx) : "v"(pX[u]), "v"(nX));
                asm("v_pk_add_f32 %0, %1, %2" : "=v"(dy) : "v"(pY[u]), "v"(nY));
                asm("v_pk_add_f32 %0, %1, %2" : "=v"(dz_) : "v"(pZ[u]), "v"(nZ));
                asm("v_pk_mul_f32 %0, %1, %1" : "=v"(xx) : "v"(dx));
                asm("v_pk_mul_f32 %0, %1, %1" : "=v"(yy) : "v"(dy));
                asm("v_pk_mul_f32 %0, %1, %1" : "=v"(zz) : "v"(dz_));
                asm("v_pk_add_f32 %0, %1, %2" : "=v"(s1) : "v"(xx), "v"(yy));
                asm("v_pk_add_f32 %0, %1, %2" : "=v"(d2) : "v"(s1), "v"(zz));
                float mx = fminf(dI[u].x, d2.x);
                float my = fminf(dI[u].y, d2.y);
                dI[u].x = mx; dI[u].y = my;
                lv = fmaxf(fmaxf(lv, mx), my);   // v_max3_f32
            }

            // lane-tie recovery: max lo among THIS lane's points at lv
            unsigned c[16];
            #pragma unroll
            for (int u = 0; u < 8; u++) {
                c[2 * u]     = (dI[u].x == lv) ? loA[u] : 0u;
                c[2 * u + 1] = (dI[u].y == lv) ? loB[u] : 0u;
            }
            #pragma unroll
            for (int st = 1; st < 16; st <<= 1)
                #pragma unroll
                for (int i = 0; i < 16; i += 2 * st)
                    c[i] = (c[i + st] > c[i]) ? c[i + st] : c[i];

            // fused lexicographic wave reduce
            ull k = ((ull)__float_as_uint(lv) << 32) | (ull)c[0];
            bestK = wave_kmax_dpp(k);
            wmaxC = __uint_as_float((unsigned)(bestK >> 32));
        }

        if (lane == 0) sKey[par][wv] = bestK;
        __syncthreads();

        ull a0 = sKey[par][0], a1 = sKey[par][1];
        ull a2 = sKey[par][2], a3 = sKey[par][3];
        ull a4 = sKey[par][4], a5 = sKey[par][5];
        ull a6 = sKey[par][6], a7 = sKey[par][7];
        a0 = (a1 > a0) ? a1 : a0;
        a2 = (a3 > a2) ? a3 : a2;
        a4 = (a5 > a4) ? a5 : a4;
        a6 = (a7 > a6) ? a7 : a6;
        a0 = (a2 > a0) ? a2 : a0;
        a4 = (a6 > a4) ? a6 : a4;
        ull kk = (a4 > a0) ? a4 : a0;

        // winner coords: broadcast LDS read via slot payload
        int slot = (int)(kk & 0x1FFFull);
        float4 c4 = sP4[slot];
        cx = c4.x; cy = c4.y; cz = c4.z;
    }

    __syncthreads();
    float4* o4 = (float4*)(out_xyz + b * Sn * 3);
    const float4* h4 = (const float4*)sHist;
    #pragma unroll
    for (int i = tid; i < Sn * 3 / 4; i += 512) o4[i] = h4[i];
}

// ---------------------------------------------------------------------------
// Ball query (unchanged; exact-decision verified: absmax 0.0).
// ---------------------------------------------------------------------------
__global__ __launch_bounds__(256) void ballq_kernel(const float* __restrict__ ws,
                                                    const float* __restrict__ newxyz,
                                                    int* __restrict__ grp) {
    #pragma clang fp contract(off)
    int t = blockIdx.x * 256 + threadIdx.x;
    int wid = t >> 6;
    int lane = t & 63;
    int b = wid >> 11;
    const float4* p4 = (const float4*)(ws + WS_P4) + b * Nn;

    float nx = newxyz[wid * 3 + 0], ny = newxyz[wid * 3 + 1], nz = newxyz[wid * 3 + 2];
    float a2 = (nx * nx + ny * ny) + nz * nz;

    int total = 0;
    int firstp = 0;
    for (int c = 0; c < Nn / 64; c++) {
        int p = c * 64 + lane;
        float4 v = p4[p];
        float x = v.x, y = v.y, z = v.z;
        float bv = (x * x + y * y) + z * z;
        float dot = __builtin_fmaf(nx, x, 0.0f);
        dot = __builtin_fmaf(ny, y, dot);
        dot = __builtin_fmaf(nz, z, dot);
        float sq = (a2 + bv) - 2.0f * dot;
        bool hit = !(sq > R2c);
        unsigned long long mask = __ballot(hit);
        if (mask) {
            if (total == 0) firstp = c * 64 + (__ffsll(mask) - 1);
            int rank = __popcll(mask & ((1ull << lane) - 1ull));
            int slot = total + rank;
            if (hit && slot < Kn) grp[wid * Kn + slot] = p;
            total += (int)__popcll(mask);
            if (total >= Kn) break;
        }
    }
    if (lane >= total && lane < Kn) grp[wid * Kn + lane] = firstp;
}

// ---------------------------------------------------------------------------
// MFMA MLP (unchanged): one group per block, 256 threads = 4 waves.
// ---------------------------------------------------------------------------
template<int KB, int O>
__device__ __forceinline__ void mfma_layer(const unsigned short* __restrict__ X,
                                           unsigned short* __restrict__ Y,
                                           const unsigned short* __restrict__ wb,
                                           const float* __restrict__ bias,
                                           int lane, int wv) {
    const int Cp = KB * 32;
    const int mt = wv & 1;
    const int mrow = mt * 16 + (lane & 15);
    const int quad = lane >> 4;

    short8 a[KB];
    #pragma unroll
    for (int kb = 0; kb < KB; kb++)
        a[kb] = *(const short8*)&X[mrow * HSTR + kb * 32 + quad * 8];

    for (int nt = (wv >> 1); nt < O / 16; nt += 2) {
        int n0 = nt * 16;
        float bv = bias[n0 + (lane & 15)];
        floatx4 acc = {bv, bv, bv, bv};
        #pragma unroll
        for (int kb = 0; kb < KB; kb++) {
            short8 bf = *(const short8*)&wb[(n0 + (lane & 15)) * Cp + kb * 32 + quad * 8];
            acc = __builtin_amdgcn_mfma_f32_16x16x32_bf16(a[kb], bf, acc, 0, 0, 0);
        }
        #pragma unroll
        for (int r = 0; r < 4; r++) {
            float v = fmaxf(acc[r], 0.f);
            int m = mt * 16 + quad * 4 + r;
            Y[m * HSTR + n0 + (lane & 15)] = f2bf(v);
        }
    }
}

__global__ __launch_bounds__(256) void mlp_kernel(const float* __restrict__ xyz,
                                                  const float* __restrict__ feat,
                                                  const float* __restrict__ ws,
                                                  const int* __restrict__ grp,
                                                  const float* __restrict__ b1,
                                                  const float* __restrict__ b2,
                                                  const float* __restrict__ b3,
                                                  float* __restrict__ out) {
    __shared__ __align__(16) unsigned short hA[32 * HSTR];
    __shared__ __align__(16) unsigned short hB[32 * HSTR];
    __shared__ float mxs[2][256];
    __shared__ int   sIdx[Kn];
    __shared__ float sCent[3];

    int g = blockIdx.x;            // b*S + s
    int b = g >> 11;
    int tid = threadIdx.x;
    int lane = tid & 63, wv = tid >> 6;

    if (tid < Kn) sIdx[tid] = grp[g * Kn + tid];
    if (tid == 0) { sCent[0] = out[g*3]; sCent[1] = out[g*3+1]; sCent[2] = out[g*3+2]; }
    // zero hA (pad cols must be 0 for the K=96 layer)
    {
        short8 z = {0,0,0,0,0,0,0,0};
        for (int i = tid; i < 32 * HSTR / 8; i += 256)
            ((short8*)hA)[i] = z;
    }
    __syncthreads();

    { // stage h0: feats -> cols 0..63 (bf16x8 vector writes), xyz -> 64..66
        int m = tid >> 3, m8 = tid & 7;
        int idx = sIdx[m];
        int base = b * Nn + idx;
        const float4* f4 = (const float4*)(feat + base * 64 + m8 * 8);
        float4 va = f4[0], vb = f4[1];
        short8 pk;
        pk[0] = (short)f2bf(va.x); pk[1] = (short)f2bf(va.y);
        pk[2] = (short)f2bf(va.z); pk[3] = (short)f2bf(va.w);
        pk[4] = (short)f2bf(vb.x); pk[5] = (short)f2bf(vb.y);
        pk[6] = (short)f2bf(vb.z); pk[7] = (short)f2bf(vb.w);
        *(short8*)&hA[m * HSTR + m8 * 8] = pk;
        if (m8 == 0) {
            hA[m * HSTR + 64] = f2bf(xyz[base * 3 + 0] - sCent[0]);
            hA[m * HSTR + 65] = f2bf(xyz[base * 3 + 1] - sCent[1]);
            hA[m * HSTR + 66] = f2bf(xyz[base * 3 + 2] - sCent[2]);
        }
    }
    __syncthreads();

    const unsigned short* wb1 = (const unsigned short*)(ws + WS_WB1);
    const unsigned short* wb2 = (const unsigned short*)(ws + WS_WB2);
    const unsigned short* wb3 = (const unsigned short*)(ws + WS_WB3);

    mfma_layer<3, 64>(hA, hB, wb1, b1, lane, wv);     // 96 -> 64
    __syncthreads();
    mfma_layer<2, 128>(hB, hA, wb2, b2, lane, wv);    // 64 -> 128
    __syncthreads();

    { // L3 (128 -> 256) + fused maxpool
        const int mt = wv & 1;
        const int mrow = mt * 16 + (lane & 15);
        const int quad = lane >> 4;
        short8 a[4];
        #pragma unroll
        for (int kb = 0; kb < 4; kb++)
            a[kb] = *(const short8*)&hA[mrow * HSTR + kb * 32 + quad * 8];
        for (int nt = (wv >> 1); nt < 16; nt += 2) {
            int n0 = nt * 16;
            float bv = b3[n0 + (lane & 15)];
            floatx4 acc = {bv, bv, bv, bv};
            #pragma unroll
            for (int kb = 0; kb < 4; kb++) {
                short8 bf = *(const short8*)&wb3[(n0 + (lane & 15)) * 128 + kb * 32 + quad * 8];
                acc = __builtin_amdgcn_mfma_f32_16x16x32_bf16(a[kb], bf, acc, 0, 0, 0);
            }
            float pm = fmaxf(fmaxf(fmaxf(acc[0], acc[1]), fmaxf(acc[2], acc[3])), 0.f);
            pm = fmaxf(pm, __shfl_xor(pm, 16));   // reduce across the 4 quads
            pm = fmaxf(pm, __shfl_xor(pm, 32));
            if (lane < 16) mxs[mt][n0 + lane] = pm;
        }
    }
    __syncthreads();

    out[OUT_XYZ + g * 256 + tid] = fmaxf(mxs[0][tid], mxs[1][tid]);
}

// ---------------------------------------------------------------------------
extern "C" void kernel_launch(void* const* d_in, const int* in_sizes, int n_in,
                              void* d_out, int out_size, void* d_ws, size_t ws_size,
                              hipStream_t stream) {
    const float* xyz  = (const float*)d_in[0];
    const float* feat = (const float*)d_in[1];
    const float* W1   = (const float*)d_in[2];
    const float* b1   = (const float*)d_in[3];
    const float* W2   = (const float*)d_in[4];
    const float* b2   = (const float*)d_in[5];
    const float* W3   = (const float*)d_in[6];
    const float* b3   = (const float*)d_in[7];
    float* out = (float*)d_out;
    float* ws  = (float*)d_ws;
    int*   grp = (int*)d_ws + WS_GRP;

    hipLaunchKernelGGL(prep_kernel, dim3(312), dim3(256), 0, stream, xyz, W1, W2, W3, ws);
    hipLaunchKernelGGL(fps_kernel, dim3(Bn), dim3(512), 0, stream, ws, out);
    hipLaunchKernelGGL(ballq_kernel, dim3(Bn * Sn / 4), dim3(256), 0, stream, ws, out, grp);
    hipLaunchKernelGGL(mlp_kernel, dim3(Bn * Sn), dim3(256), 0, stream,
                       xyz, feat, ws, grp, b1, b2, b3, out);
}